// Round 1
// baseline (821.029 us; speedup 1.0000x reference)
//
#include <hip/hip_runtime.h>

#define NCLS 19
#define IGN 255
#define C_DIM 256
#define HW 32768            // 128*256
#define PIX 262144          // 8*128*256
#define PAIRS (PIX/2)       // 131072
#define PS (NCLS*C_DIM + NCLS)   // 4883 floats per block partial

// ws float offsets
#define WS_ACC 0            // 4 floats: sum_wl, sum_vw, sum_simv, sum_v
#define WS_PROT 8           // 19*256 normalized prototypes
#define WS_PV  4872         // 19 valid flags
#define WS_PART 4896        // NBA * PS partials

// out float offsets
#define O_LOSS 0
#define O_SIM  1
#define O_WL   (1 + PIX)
#define O_MS   (1 + 2*PIX)
#define O_PN   (2 + 2*PIX)
#define O_PV   (2 + 2*PIX + NCLS)

__global__ __launch_bounds__(256) void protoAccum(const float* __restrict__ t,
                                                  const int* __restrict__ mask,
                                                  float* __restrict__ part) {
    __shared__ float ls[NCLS * 257];
    __shared__ float lc[NCLS];
    const int tid = threadIdx.x;
    for (int i = tid; i < NCLS * 257; i += 256) ls[i] = 0.f;
    if (tid < NCLS) lc[tid] = 0.f;
    __syncthreads();

    for (int idx = blockIdx.x * 256 + tid; idx < PAIRS; idx += gridDim.x * 256) {
        const int p0 = idx * 2;
        const int b = p0 >> 15;
        const int hw = p0 & (HW - 1);
        const int2 kk = *(const int2*)(mask + p0);
        const bool v0 = (kk.x != IGN);
        const bool v1 = (kk.y != IGN);
        if (v0) atomicAdd(&lc[kk.x], 1.f);
        if (v1) atomicAdd(&lc[kk.y], 1.f);
        const int b0 = v0 ? kk.x * 257 : 0;
        const int b1 = v1 ? kk.y * 257 : 0;
        const float* tb = t + (size_t)b * C_DIM * HW + hw;
        #pragma unroll 4
        for (int c = 0; c < C_DIM; ++c) {
            const float2 v = *(const float2*)(tb + (size_t)c * HW);
            if (v0) atomicAdd(&ls[b0 + c], v.x);
            if (v1) atomicAdd(&ls[b1 + c], v.y);
        }
    }
    __syncthreads();

    float* pb = part + (size_t)blockIdx.x * PS;
    for (int i = tid; i < NCLS * C_DIM; i += 256) {
        const int k = i >> 8, c = i & 255;
        pb[i] = ls[k * 257 + c];
    }
    if (tid < NCLS) pb[NCLS * C_DIM + tid] = lc[tid];
}

__global__ __launch_bounds__(1024) void protoReduce(const float* __restrict__ part, int nb,
                                                    float* __restrict__ ws,
                                                    float* __restrict__ out) {
    __shared__ float red[1024];
    __shared__ float s4[4][C_DIM];
    const int k = blockIdx.x;
    const int tid = threadIdx.x;
    const int c = tid & 255;
    const int g = tid >> 8;

    // class count
    float cp = 0.f;
    for (int b = tid; b < nb; b += 1024) cp += part[(size_t)b * PS + NCLS * C_DIM + k];
    red[tid] = cp; __syncthreads();
    for (int s = 512; s > 0; s >>= 1) { if (tid < s) red[tid] += red[tid + s]; __syncthreads(); }
    const float cnt = red[0]; __syncthreads();

    // class feature sum
    float sp = 0.f;
    for (int b = g; b < nb; b += 4) sp += part[(size_t)b * PS + k * C_DIM + c];
    s4[g][c] = sp; __syncthreads();
    float raw = s4[0][c] + s4[1][c] + s4[2][c] + s4[3][c];
    raw = (cnt > 0.f) ? (raw / fmaxf(cnt, 1.f)) : 0.f;

    // norm of raw prototype
    red[tid] = (g == 0) ? raw * raw : 0.f; __syncthreads();
    for (int s = 512; s > 0; s >>= 1) { if (tid < s) red[tid] += red[tid + s]; __syncthreads(); }
    const float n1 = sqrtf(red[0]); __syncthreads();
    const float p = raw / fmaxf(n1, 1e-6f);
    if (g == 0) ws[WS_PROT + k * C_DIM + c] = p;

    // norm of normalized prototype (what the reference reports)
    red[tid] = (g == 0) ? p * p : 0.f; __syncthreads();
    for (int s = 512; s > 0; s >>= 1) { if (tid < s) red[tid] += red[tid + s]; __syncthreads(); }
    if (tid == 0) {
        const float pn = sqrtf(red[0]);
        out[O_PN + k] = pn;
        const float pv = (pn > 0.f) ? 1.f : 0.f;
        out[O_PV + k] = pv;
        ws[WS_PV + k] = pv;
        if (k == 0) { ws[WS_ACC+0] = 0.f; ws[WS_ACC+1] = 0.f; ws[WS_ACC+2] = 0.f; ws[WS_ACC+3] = 0.f; }
    }
}

__global__ __launch_bounds__(256) void simLoss(const float* __restrict__ s,
                                               const int* __restrict__ mask,
                                               const float* __restrict__ swt,
                                               const float* __restrict__ ws,
                                               float* __restrict__ out,
                                               float* __restrict__ acc) {
    __shared__ float lp[NCLS * 257];
    __shared__ float lpv[NCLS];
    __shared__ float redw[256];
    const int tid = threadIdx.x;
    for (int i = tid; i < NCLS * C_DIM; i += 256)
        lp[(i >> 8) * 257 + (i & 255)] = ws[WS_PROT + i];
    if (tid < NCLS) lpv[tid] = ws[WS_PV + tid];
    __syncthreads();

    float s_wl = 0.f, s_vw = 0.f, s_sv = 0.f, s_v = 0.f;
    const int idx = blockIdx.x * 256 + tid;
    if (idx < PAIRS) {
        const int p0 = idx * 2;
        const int b = p0 >> 15;
        const int hw = p0 & (HW - 1);
        const int2 kk = *(const int2*)(mask + p0);
        const float2 sw = *(const float2*)(swt + p0);
        const bool v0 = (kk.x != IGN), v1 = (kk.y != IGN);
        const int k0 = v0 ? kk.x : 0;
        const int k1 = v1 ? kk.y : 0;
        const int b0 = k0 * 257, b1 = k1 * 257;
        const float* sb = s + (size_t)b * C_DIM * HW + hw;
        float d0 = 0.f, d1 = 0.f, q0 = 0.f, q1 = 0.f;
        #pragma unroll 8
        for (int c = 0; c < C_DIM; ++c) {
            const float2 v = *(const float2*)(sb + (size_t)c * HW);
            d0 += v.x * lp[b0 + c];
            q0 += v.x * v.x;
            d1 += v.y * lp[b1 + c];
            q1 += v.y * v.y;
        }
        const float sim0 = d0 / fmaxf(sqrtf(q0), 1e-12f);
        const float sim1 = d1 / fmaxf(sqrtf(q1), 1e-12f);
        const float vm0 = (v0 && lpv[k0] > 0.f) ? 1.f : 0.f;
        const float vm1 = (v1 && lpv[k1] > 0.f) ? 1.f : 0.f;
        const float wl0 = (1.f - sim0) * vm0 * sw.x;
        const float wl1 = (1.f - sim1) * vm1 * sw.y;
        out[O_SIM + p0]     = sim0;
        out[O_SIM + p0 + 1] = sim1;
        out[O_WL + p0]      = wl0;
        out[O_WL + p0 + 1]  = wl1;
        s_wl = wl0 + wl1;
        s_vw = vm0 * sw.x + vm1 * sw.y;
        s_sv = sim0 * vm0 + sim1 * vm1;
        s_v  = vm0 + vm1;
    }

    // 4 block reductions + one atomic each
    float vals[4] = { s_wl, s_vw, s_sv, s_v };
    #pragma unroll
    for (int r = 0; r < 4; ++r) {
        redw[tid] = vals[r]; __syncthreads();
        for (int s2 = 128; s2 > 0; s2 >>= 1) {
            if (tid < s2) redw[tid] += redw[tid + s2];
            __syncthreads();
        }
        if (tid == 0) atomicAdd(&acc[r], redw[0]);
        __syncthreads();
    }
}

__global__ void finalK(const float* __restrict__ acc, float* __restrict__ out) {
    if (threadIdx.x == 0 && blockIdx.x == 0) {
        out[O_LOSS] = acc[0] / fmaxf(acc[1], 1.f);
        out[O_MS]   = acc[2] / fmaxf(acc[3], 1.f);
    }
}

extern "C" void kernel_launch(void* const* d_in, const int* in_sizes, int n_in,
                              void* d_out, int out_size, void* d_ws, size_t ws_size,
                              hipStream_t stream) {
    const float* s_feat = (const float*)d_in[0];
    const float* t_feat = (const float*)d_in[1];
    const int*   mask   = (const int*)d_in[2];
    const float* swt    = (const float*)d_in[3];
    float* out = (float*)d_out;
    float* ws  = (float*)d_ws;

    // how many partial blocks fit in ws
    int NBA = 512;
    {
        const size_t avail = ws_size / 4;
        if (avail > (size_t)WS_PART) {
            const size_t fit = (avail - WS_PART) / PS;
            if (fit < (size_t)NBA) NBA = (int)(fit > 0 ? fit : 1);
        } else {
            NBA = 1;
        }
    }
    float* part = ws + WS_PART;

    protoAccum<<<NBA, 256, 0, stream>>>(t_feat, mask, part);
    protoReduce<<<NCLS, 1024, 0, stream>>>(part, NBA, ws, out);
    simLoss<<<(PAIRS + 255) / 256, 256, 0, stream>>>(s_feat, mask, swt, ws, out, ws + WS_ACC);
    finalK<<<1, 64, 0, stream>>>(ws + WS_ACC, out);
}

// Round 3
// 777.655 us; speedup vs baseline: 1.0558x; 1.0558x over previous
//
#include <hip/hip_runtime.h>

#define NCLS 19
#define IGN 255
#define C_DIM 256
#define HW 32768            // 128*256
#define PIX 262144          // 8*128*256
#define TPX 256             // pixels per block tile
#define CCH 8               // channels per chunk
#define NCHUNK 32           // C_DIM / CCH
#define TSTR 258            // LDS tile row stride (words)

// ws word offsets
#define WS_ACC 0            // 4 scalar accumulators
#define WS_GSUM 16          // 19*256 class-channel sums
#define WS_GCNT (WS_GSUM + NCLS*C_DIM)   // 4880: 19 counts
#define WS_PROT 4900        // 19*256 normalized prototypes
#define WS_PV   (WS_PROT + NCLS*C_DIM)   // 9764: 19 valid flags

// out word offsets
#define O_LOSS 0
#define O_SIM  1
#define O_WL   (1 + PIX)
#define O_MS   (1 + 2*PIX)
#define O_PN   (2 + 2*PIX)
#define O_PV   (2 + 2*PIX + NCLS)

__global__ __launch_bounds__(256, 4) void protoAccum(const float* __restrict__ t,
                                                     const int* __restrict__ mask,
                                                     float* __restrict__ gsum,
                                                     float* __restrict__ gcnt) {
    __shared__ float tile[CCH * TSTR];        // 2064 words
    __shared__ float acc[NCLS * 257];         // 4883 words
    __shared__ float cnt[NCLS];
    const int tid = threadIdx.x;
    for (int i = tid; i < NCLS * 257; i += 256) acc[i] = 0.f;
    if (tid < NCLS) cnt[tid] = 0.f;

    const int px0 = blockIdx.x * TPX;
    const int b = px0 >> 15;
    const int hw0 = px0 & (HW - 1);
    const float* tb = t + (size_t)b * C_DIM * HW + hw0;

    const int pbase = tid & 31;   // pixel slot
    const int g = tid >> 5;       // c-group 0..7

    int   cls[8];
    float fva[8];
    #pragma unroll
    for (int j = 0; j < 8; ++j) {
        const int m = mask[px0 + pbase + 32 * j];
        const bool v = (m != IGN);
        cls[j] = v ? m : 0;
        fva[j] = v ? 1.f : 0.f;
    }

    // preload chunk 0 into regs
    float2 r[4];
    #pragma unroll
    for (int k = 0; k < 4; ++k) {
        const int e = tid + 256 * k;
        r[k] = *(const float2*)(tb + (size_t)(e >> 7) * HW + 2 * (e & 127));
    }
    __syncthreads();   // zeros visible

    if (g == 0) {
        #pragma unroll
        for (int j = 0; j < 8; ++j) atomicAdd(&cnt[cls[j]], fva[j]);
    }

    for (int n = 0; n < NCHUNK; ++n) {
        #pragma unroll
        for (int k = 0; k < 4; ++k) {
            const int e = tid + 256 * k;
            *(float2*)&tile[(e >> 7) * TSTR + 2 * (e & 127)] = r[k];
        }
        if (n + 1 < NCHUNK) {
            const float* tc = tb + (size_t)(n + 1) * CCH * HW;
            #pragma unroll
            for (int k = 0; k < 4; ++k) {
                const int e = tid + 256 * k;
                r[k] = *(const float2*)(tc + (size_t)(e >> 7) * HW + 2 * (e & 127));
            }
        }
        __syncthreads();   // tile ready
        const int cglob = n * CCH + g;
        #pragma unroll
        for (int j = 0; j < 8; ++j) {
            const float v = tile[g * TSTR + pbase + 32 * j];
            atomicAdd(&acc[cls[j] * 257 + cglob], v * fva[j]);
        }
        __syncthreads();   // tile free
    }

    // flush block partials to global accumulator
    for (int i = tid; i < NCLS * C_DIM; i += 256) {
        const int k = i >> 8, c = i & 255;
        atomicAdd(&gsum[i], acc[k * 257 + c]);
    }
    if (tid < NCLS) atomicAdd(&gcnt[tid], cnt[tid]);
}

__global__ __launch_bounds__(256) void protoReduce(const float* __restrict__ gsum,
                                                   const float* __restrict__ gcnt,
                                                   float* __restrict__ ws,
                                                   float* __restrict__ out) {
    __shared__ float wr[4], wr2[4];
    const int k = blockIdx.x;
    const int tid = threadIdx.x;
    const int lane = tid & 63, wv = tid >> 6;

    const float cn = gcnt[k];
    const float raw = gsum[k * 256 + tid];
    const float mean = (cn > 0.f) ? raw / fmaxf(cn, 1.f) : 0.f;

    float v = mean * mean;
    #pragma unroll
    for (int o = 32; o > 0; o >>= 1) v += __shfl_down(v, o);
    if (lane == 0) wr[wv] = v;
    __syncthreads();
    const float S = wr[0] + wr[1] + wr[2] + wr[3];
    const float p = mean / fmaxf(sqrtf(S), 1e-6f);
    ws[WS_PROT + k * 256 + tid] = p;

    float v2 = p * p;
    #pragma unroll
    for (int o = 32; o > 0; o >>= 1) v2 += __shfl_down(v2, o);
    if (lane == 0) wr2[wv] = v2;
    __syncthreads();
    if (tid == 0) {
        const float pn = sqrtf(wr2[0] + wr2[1] + wr2[2] + wr2[3]);
        out[O_PN + k] = pn;
        const float pvv = (pn > 0.f) ? 1.f : 0.f;
        out[O_PV + k] = pvv;
        ws[WS_PV + k] = pvv;
    }
}

__global__ __launch_bounds__(256, 4) void simLoss(const float* __restrict__ s,
                                                  const int* __restrict__ mask,
                                                  const float* __restrict__ swt,
                                                  const float* __restrict__ ws,
                                                  float* __restrict__ out,
                                                  float* __restrict__ acc4) {
    __shared__ float sm[CCH * TSTR + NCLS * 257];   // tile @0 (2064), proto @2064; red overlays @0 (4096)
    __shared__ float pv[NCLS];
    __shared__ float wred[4][4];
    float* tile = sm;
    float* proto = sm + CCH * TSTR;

    const int tid = threadIdx.x;
    for (int i = tid; i < NCLS * C_DIM; i += 256)
        proto[(i >> 8) * 257 + (i & 255)] = ws[WS_PROT + i];
    if (tid < NCLS) pv[tid] = ws[WS_PV + tid];

    const int px0 = blockIdx.x * TPX;
    const int b = px0 >> 15;
    const int hw0 = px0 & (HW - 1);
    const float* sb = s + (size_t)b * C_DIM * HW + hw0;

    const int pbase = tid & 31;
    const int g = tid >> 5;

    int mreg[8];
    #pragma unroll
    for (int j = 0; j < 8; ++j) mreg[j] = mask[px0 + pbase + 32 * j];

    float2 r[4];
    #pragma unroll
    for (int k = 0; k < 4; ++k) {
        const int e = tid + 256 * k;
        r[k] = *(const float2*)(sb + (size_t)(e >> 7) * HW + 2 * (e & 127));
    }
    __syncthreads();   // proto/pv ready

    int cls[8];
    #pragma unroll
    for (int j = 0; j < 8; ++j) cls[j] = (mreg[j] != IGN) ? mreg[j] : 0;

    float d[8], q[8];
    #pragma unroll
    for (int j = 0; j < 8; ++j) { d[j] = 0.f; q[j] = 0.f; }

    for (int n = 0; n < NCHUNK; ++n) {
        #pragma unroll
        for (int k = 0; k < 4; ++k) {
            const int e = tid + 256 * k;
            *(float2*)&tile[(e >> 7) * TSTR + 2 * (e & 127)] = r[k];
        }
        if (n + 1 < NCHUNK) {
            const float* sc = sb + (size_t)(n + 1) * CCH * HW;
            #pragma unroll
            for (int k = 0; k < 4; ++k) {
                const int e = tid + 256 * k;
                r[k] = *(const float2*)(sc + (size_t)(e >> 7) * HW + 2 * (e & 127));
            }
        }
        __syncthreads();   // tile ready
        const int cglob = n * CCH + g;
        #pragma unroll
        for (int j = 0; j < 8; ++j) {
            const float v = tile[g * TSTR + pbase + 32 * j];
            d[j] += v * proto[cls[j] * 257 + cglob];
            q[j] += v * v;
        }
        __syncthreads();   // tile free
    }

    // cross c-group reduction of (d,q): red[g][px] overlays sm[0..4096)
    #pragma unroll
    for (int j = 0; j < 8; ++j) {
        float2 w; w.x = d[j]; w.y = q[j];
        *(float2*)&sm[g * (TPX * 2) + (pbase + 32 * j) * 2] = w;
    }
    __syncthreads();

    float dt = 0.f, qt = 0.f;
    #pragma unroll
    for (int gg = 0; gg < 8; ++gg) {
        const float2 w = *(const float2*)&sm[gg * (TPX * 2) + tid * 2];
        dt += w.x; qt += w.y;
    }

    const int mp = mask[px0 + tid];
    const bool vp = (mp != IGN);
    const int kp = vp ? mp : 0;
    const float vm = (vp && pv[kp] > 0.f) ? 1.f : 0.f;
    const float sw = swt[px0 + tid];
    const float sim = dt / fmaxf(sqrtf(qt), 1e-12f);
    const float wl = (1.f - sim) * vm * sw;
    out[O_SIM + px0 + tid] = sim;
    out[O_WL + px0 + tid] = wl;

    float vals[4] = { wl, vm * sw, sim * vm, vm };
    const int lane = tid & 63, wv = tid >> 6;
    #pragma unroll
    for (int rr = 0; rr < 4; ++rr) {
        float x = vals[rr];
        #pragma unroll
        for (int o = 32; o > 0; o >>= 1) x += __shfl_down(x, o);
        if (lane == 0) wred[wv][rr] = x;
    }
    __syncthreads();
    if (tid < 4) {
        const float sumv = wred[0][tid] + wred[1][tid] + wred[2][tid] + wred[3][tid];
        atomicAdd(&acc4[tid], sumv);
    }
}

__global__ void finalK(const float* __restrict__ acc, float* __restrict__ out) {
    if (threadIdx.x == 0 && blockIdx.x == 0) {
        out[O_LOSS] = acc[0] / fmaxf(acc[1], 1.f);
        out[O_MS]   = acc[2] / fmaxf(acc[3], 1.f);
    }
}

extern "C" void kernel_launch(void* const* d_in, const int* in_sizes, int n_in,
                              void* d_out, int out_size, void* d_ws, size_t ws_size,
                              hipStream_t stream) {
    const float* s_feat = (const float*)d_in[0];
    const float* t_feat = (const float*)d_in[1];
    const int*   mask   = (const int*)d_in[2];
    const float* swt    = (const float*)d_in[3];
    float* out = (float*)d_out;
    float* ws  = (float*)d_ws;

    // zero scalar acc + class sums/counts
    hipMemsetAsync(ws, 0, (size_t)WS_PROT * sizeof(float), stream);

    protoAccum<<<PIX / TPX, 256, 0, stream>>>(t_feat, mask, ws + WS_GSUM, ws + WS_GCNT);
    protoReduce<<<NCLS, 256, 0, stream>>>(ws + WS_GSUM, ws + WS_GCNT, ws, out);
    simLoss<<<PIX / TPX, 256, 0, stream>>>(s_feat, mask, swt, ws, out, ws + WS_ACC);
    finalK<<<1, 64, 0, stream>>>(ws + WS_ACC, out);
}